// Round 10
// baseline (473.117 us; speedup 1.0000x reference)
//
#include <hip/hip_runtime.h>
#include <math.h>

#define N_NODES 50000
#define N_EDGES 800000
#define EA (N_EDGES + N_NODES)   /* edges + self loops = 850000 */
#define HEADS 4
#define HID 64
#define NG 64
#define NEG_SLOPE 0.2f
#define SCAN_CHUNK 1024
#define NBLK ((N_NODES + SCAN_CHUNK - 1) / SCAN_CHUNK)   /* 49 */

typedef _Float16 f16x8 __attribute__((ext_vector_type(8)));
typedef float f32x4 __attribute__((ext_vector_type(4)));

__device__ inline float lrelu(float x) { return x > 0.f ? x : NEG_SLOPE * x; }

// MFMA 16x16x32 f16 operand fragment: elem j -> k = 16*(j>>2) + lq*4 + (j&3)
__device__ inline f16x8 ldfrag(const _Float16* __restrict__ p, int lq) {
    uint2 lo = *(const uint2*)(p + lq * 4);
    uint2 hi = *(const uint2*)(p + 16 + lq * 4);
    union { uint4 u; f16x8 v; } f;
    f.u = make_uint4(lo.x, lo.y, hi.x, hi.y);
    return f.v;
}

// ---------------- CSR build ----------------
__global__ void k_zero(int* __restrict__ deg, float* __restrict__ pooled,
                       float* __restrict__ cnt)
{
    int i = blockIdx.x * 256 + threadIdx.x;
    int st = gridDim.x * 256;
    for (int j = i; j < N_NODES; j += st) deg[j] = 0;
    if (i < NG * HID) pooled[i] = 0.f;
    if (i < NG) cnt[i] = 0.f;
}

__global__ void k_deg(const int* __restrict__ ei, int* __restrict__ deg)
{
    int e = blockIdx.x * 256 + threadIdx.x;
    if (e >= EA) return;
    int d = (e < N_EDGES) ? ei[N_EDGES + e] : e - N_EDGES;
    atomicAdd(&deg[d], 1);
}

__global__ __launch_bounds__(1024) void k_scan1(const int* __restrict__ deg,
        int* __restrict__ incl, int* __restrict__ blksum)
{
    __shared__ int sd[SCAN_CHUNK];
    int t = threadIdx.x;
    int i = blockIdx.x * SCAN_CHUNK + t;
    sd[t] = (i < N_NODES) ? deg[i] : 0;
    for (int off = 1; off < SCAN_CHUNK; off <<= 1) {
        __syncthreads();
        int u = (t >= off) ? sd[t - off] : 0;
        __syncthreads();
        sd[t] += u;
    }
    if (i < N_NODES) incl[i] = sd[t];
    if (t == SCAN_CHUNK - 1) blksum[blockIdx.x] = sd[t];
}

// ---------- scan2 + weight prep fused (1 block, 256 threads) ----------
// W1P[n'=c*4+h][k] = W1[k][h*64+c]                       (256x64 fp16)
// W2P[n][k'=c*4+h] = W2[h*64+c][n]                       (64x256 fp16)
// va1s[k*4+h] = sum_c W1[k][h*64+c]*a1s[h][c]            (fp32)
// b1P[k'] = b1[h*64+c];  va2sP[k'] = sum_c2 W2[h*64+c][c2]*a2s[c2]
__global__ __launch_bounds__(256) void k_scan2p(const int* __restrict__ blksum,
        int* __restrict__ blkoff, const float* __restrict__ W1,
        const float* __restrict__ a1s, const float* __restrict__ a1d,
        const float* __restrict__ W2, const float* __restrict__ a2s,
        const float* __restrict__ a2d, const float* __restrict__ b1,
        _Float16* __restrict__ W1P, _Float16* __restrict__ W2P,
        float* __restrict__ va1s, float* __restrict__ va1d,
        float* __restrict__ b1P, float* __restrict__ va2sP, float* __restrict__ va2dP)
{
    const int t = threadIdx.x;
    if (t == 0) {
        int acc = 0;
        for (int b = 0; b < NBLK; ++b) { blkoff[b] = acc; acc += blksum[b]; }
    }
    for (int i = t; i < 256 * 64; i += 256) {
        int np = i >> 6, k = i & 63;
        W1P[i] = (_Float16)W1[k * 256 + (np & 3) * 64 + (np >> 2)];
    }
    for (int i = t; i < 64 * 256; i += 256) {
        int n = i >> 8, kp = i & 255;
        W2P[i] = (_Float16)W2[((kp & 3) * 64 + (kp >> 2)) * 64 + n];
    }
    {
        int k = t >> 2, h = t & 3;
        float ss = 0.f, sd = 0.f;
        for (int c = 0; c < 64; ++c) {
            float wv = W1[k * 256 + h * 64 + c];
            ss = fmaf(wv, a1s[h * 64 + c], ss);
            sd = fmaf(wv, a1d[h * 64 + c], sd);
        }
        va1s[t] = ss;   // layout [k][h]
        va1d[t] = sd;
    }
    {
        int ko = (t & 3) * 64 + (t >> 2);   // orig k for k'=t
        b1P[t] = b1[ko];
        float ss = 0.f, sd = 0.f;
        for (int c = 0; c < 64; ++c) {
            float wv = W2[ko * 64 + c];
            ss = fmaf(wv, a2s[c], ss);
            sd = fmaf(wv, a2d[c], sd);
        }
        va2sP[t] = ss;
        va2dP[t] = sd;
    }
}

__global__ void k_scan3(const int* __restrict__ incl, const int* __restrict__ blkoff,
                        const int* __restrict__ deg, const int* __restrict__ batch,
                        int* __restrict__ rowptr, int* __restrict__ cursor,
                        float* __restrict__ cnt)
{
    int i = blockIdx.x * 256 + threadIdx.x;
    bool act = i < N_NODES;
    if (act) {
        int v = incl[i] + blkoff[i >> 10];
        rowptr[i + 1] = v;
        cursor[i] = v - deg[i];
        if (i == 0) rowptr[0] = 0;
    }
    int g = act ? batch[i] : -1;
    int lane = threadIdx.x & 63;
    int g0 = __shfl(g, 0, 64);
    if (__all(g == g0)) {
        if (lane == 0 && g0 >= 0) atomicAdd(&cnt[g0], 64.f);
    } else if (act) {
        atomicAdd(&cnt[g], 1.f);
    }
}

__global__ void k_fill(const int* __restrict__ ei, int* __restrict__ cursor,
                       int* __restrict__ csr_src)
{
    int e = blockIdx.x * 256 + threadIdx.x;
    if (e >= EA) return;
    int s, d;
    if (e < N_EDGES) { s = ei[e]; d = ei[N_EDGES + e]; }
    else { s = e - N_EDGES; d = s; }
    int pos = atomicAdd(&cursor[d], 1);
    csr_src[pos] = s;
}

// ---------- conv1 GEMM via MFMA, fused fp32->fp16 cast + exact fp32 scores ----------
__global__ __launch_bounds__(256) void k_gemm1(const float* __restrict__ x,
        const _Float16* __restrict__ W1P, const float* __restrict__ va1s,
        const float* __restrict__ va1d, _Float16* __restrict__ xp1h,
        float* __restrict__ e1s, float* __restrict__ e1d)
{
    const int t = threadIdx.x;
    const int lane = t & 63, w = t >> 6;
    const int l15 = lane & 15, lq = lane >> 4;
    const int m0 = blockIdx.x * 64 + w * 16;
    const int mrow = m0 + l15;
    const int mc = mrow < N_NODES ? mrow : N_NODES - 1;
    const float* xr = x + (size_t)mc * 64;
    float4 x0 = *(const float4*)(xr + lq * 4);
    float4 x1 = *(const float4*)(xr + 16 + lq * 4);
    float4 x2 = *(const float4*)(xr + 32 + lq * 4);
    float4 x3 = *(const float4*)(xr + 48 + lq * 4);
    // exact fp32 scores: partial over this lane's 16 k's, reduce over lq groups
    const float4* vs4 = (const float4*)va1s;
    const float4* vd4 = (const float4*)va1d;
    float4 es = {0,0,0,0}, ed = {0,0,0,0};
    {
        float xv[16] = {x0.x,x0.y,x0.z,x0.w, x1.x,x1.y,x1.z,x1.w,
                        x2.x,x2.y,x2.z,x2.w, x3.x,x3.y,x3.z,x3.w};
        #pragma unroll
        for (int q = 0; q < 4; ++q) {
            int kb = q * 16 + lq * 4;
            #pragma unroll
            for (int j = 0; j < 4; ++j) {
                float v = xv[q * 4 + j];
                float4 a = vs4[kb + j], b = vd4[kb + j];
                es.x = fmaf(v, a.x, es.x); es.y = fmaf(v, a.y, es.y);
                es.z = fmaf(v, a.z, es.z); es.w = fmaf(v, a.w, es.w);
                ed.x = fmaf(v, b.x, ed.x); ed.y = fmaf(v, b.y, ed.y);
                ed.z = fmaf(v, b.z, ed.z); ed.w = fmaf(v, b.w, ed.w);
            }
        }
    }
    #pragma unroll
    for (int off = 16; off <= 32; off <<= 1) {
        es.x += __shfl_down(es.x, off, 64); es.y += __shfl_down(es.y, off, 64);
        es.z += __shfl_down(es.z, off, 64); es.w += __shfl_down(es.w, off, 64);
        ed.x += __shfl_down(ed.x, off, 64); ed.y += __shfl_down(ed.y, off, 64);
        ed.z += __shfl_down(ed.z, off, 64); ed.w += __shfl_down(ed.w, off, 64);
    }
    if (lq == 0 && mrow < N_NODES) {
        ((float4*)e1s)[mrow] = es;
        ((float4*)e1d)[mrow] = ed;
    }
    // fp16 fragments (same element order as ldfrag)
    union { f16x8 v; _Float16 e[8]; } u0, u1;
    u0.e[0]=(_Float16)x0.x; u0.e[1]=(_Float16)x0.y; u0.e[2]=(_Float16)x0.z; u0.e[3]=(_Float16)x0.w;
    u0.e[4]=(_Float16)x1.x; u0.e[5]=(_Float16)x1.y; u0.e[6]=(_Float16)x1.z; u0.e[7]=(_Float16)x1.w;
    u1.e[0]=(_Float16)x2.x; u1.e[1]=(_Float16)x2.y; u1.e[2]=(_Float16)x2.z; u1.e[3]=(_Float16)x2.w;
    u1.e[4]=(_Float16)x3.x; u1.e[5]=(_Float16)x3.y; u1.e[6]=(_Float16)x3.z; u1.e[7]=(_Float16)x3.w;
    #pragma unroll
    for (int ct = 0; ct < 16; ++ct) {
        const _Float16* wrow = W1P + (size_t)(ct * 16 + l15) * 64;
        f16x8 wf0 = ldfrag(wrow, lq);
        f16x8 wf1 = ldfrag(wrow + 32, lq);
        f32x4 acc = {0.f, 0.f, 0.f, 0.f};
        acc = __builtin_amdgcn_mfma_f32_16x16x32_f16(wf0, u0.v, acc, 0, 0, 0);
        acc = __builtin_amdgcn_mfma_f32_16x16x32_f16(wf1, u1.v, acc, 0, 0, 0);
        if (mrow < N_NODES) {
            union { uint2 u2; _Float16 e[4]; } o;
            o.e[0]=(_Float16)acc[0]; o.e[1]=(_Float16)acc[1];
            o.e[2]=(_Float16)acc[2]; o.e[3]=(_Float16)acc[3];
            *(uint2*)(xp1h + (size_t)mrow * 256 + ct * 16 + lq * 4) = o.u2;
        }
    }
}

// ---------- aggr1: edge-paired (2 edges/iter via wave halves), 16B gathers ----------
// writes h1h in [c*4+h] interleave; fused bias+ELU + exact fp32 conv2 scores
__global__ __launch_bounds__(256) void k_aggr1(const int* __restrict__ rowptr,
        const int* __restrict__ csr_src, const float* __restrict__ e1s,
        const float* __restrict__ e1d, const _Float16* __restrict__ xp1h,
        const float* __restrict__ b1P, const float* __restrict__ va2sP,
        const float* __restrict__ va2dP, _Float16* __restrict__ h1h,
        float* __restrict__ e2s_o, float* __restrict__ e2d_o)
{
    const int lane = threadIdx.x & 63;
    const int w = __builtin_amdgcn_readfirstlane(threadIdx.x >> 6);
    const int d = blockIdx.x * 4 + w;
    if (d >= N_NODES) return;
    const int beg = rowptr[d], end = rowptr[d + 1];
    const float4 edv = ((const float4*)e1d)[d];
    const int li = lane & 31;
    const bool hB = lane >= 32;
    float acc[8] = {0,0,0,0,0,0,0,0};
    float den[4] = {0,0,0,0};
    for (int jb = beg; jb < end; jb += 64) {
        int myj = jb + lane;
        int sv = 0;
        float px = 0.f, py = 0.f, pz = 0.f, pw = 0.f;
        if (myj < end) {
            sv = csr_src[myj];
            float4 q = ((const float4*)e1s)[sv];
            px = __expf(lrelu(q.x + edv.x));
            py = __expf(lrelu(q.y + edv.y));
            pz = __expf(lrelu(q.z + edv.z));
            pw = __expf(lrelu(q.w + edv.w));
        }
        int nj = end - jb; if (nj > 64) nj = 64;
        int pr = (nj + 7) & ~7;          // round to 4 pairs
        for (int j = 0; j < pr; j += 8) {
            #pragma unroll
            for (int u = 0; u < 4; ++u) {
                int eA = j + 2 * u, eB = eA + 1;
                int sA = __shfl(sv, eA, 64), sB = __shfl(sv, eB, 64);
                float pxA = __shfl(px, eA, 64), pxB = __shfl(px, eB, 64);
                float pyA = __shfl(py, eA, 64), pyB = __shfl(py, eB, 64);
                float pzA = __shfl(pz, eA, 64), pzB = __shfl(pz, eB, 64);
                float pwA = __shfl(pw, eA, 64), pwB = __shfl(pw, eB, 64);
                int s = hB ? sB : sA;
                float p0 = hB ? pxB : pxA, p1 = hB ? pyB : pyA;
                float p2 = hB ? pzB : pzA, p3 = hB ? pwB : pwA;
                union { uint4 u4; _Float16 e[8]; } X;
                X.u4 = *(const uint4*)(xp1h + (size_t)s * 256 + li * 8);
                acc[0] = fmaf(p0, (float)X.e[0], acc[0]);
                acc[1] = fmaf(p1, (float)X.e[1], acc[1]);
                acc[2] = fmaf(p2, (float)X.e[2], acc[2]);
                acc[3] = fmaf(p3, (float)X.e[3], acc[3]);
                acc[4] = fmaf(p0, (float)X.e[4], acc[4]);
                acc[5] = fmaf(p1, (float)X.e[5], acc[5]);
                acc[6] = fmaf(p2, (float)X.e[6], acc[6]);
                acc[7] = fmaf(p3, (float)X.e[7], acc[7]);
                den[0] += p0; den[1] += p1; den[2] += p2; den[3] += p3;
            }
        }
    }
    #pragma unroll
    for (int j = 0; j < 8; ++j) acc[j] += __shfl_xor(acc[j], 32, 64);
    #pragma unroll
    for (int h = 0; h < 4; ++h) den[h] += __shfl_xor(den[h], 32, 64);
    float rd[4] = {1.f / den[0], 1.f / den[1], 1.f / den[2], 1.f / den[3]};
    float4 bl = ((const float4*)b1P)[2 * li],  bh = ((const float4*)b1P)[2 * li + 1];
    float4 sl = ((const float4*)va2sP)[2 * li], sh = ((const float4*)va2sP)[2 * li + 1];
    float4 dl = ((const float4*)va2dP)[2 * li], dh = ((const float4*)va2dP)[2 * li + 1];
    float bb[8] = {bl.x,bl.y,bl.z,bl.w, bh.x,bh.y,bh.z,bh.w};
    float ss[8] = {sl.x,sl.y,sl.z,sl.w, sh.x,sh.y,sh.z,sh.w};
    float dd[8] = {dl.x,dl.y,dl.z,dl.w, dh.x,dh.y,dh.z,dh.w};
    float es = 0.f, edd = 0.f;
    union { uint4 u4; _Float16 e[8]; } O;
    #pragma unroll
    for (int j = 0; j < 8; ++j) {
        float v = acc[j] * rd[j & 3] + bb[j];
        v = v > 0.f ? v : __expf(v) - 1.f;
        O.e[j] = (_Float16)v;
        es  = fmaf(v, ss[j], es);
        edd = fmaf(v, dd[j], edd);
    }
    if (!hB) *(uint4*)(h1h + (size_t)d * 256 + li * 8) = O.u4;
    #pragma unroll
    for (int off = 32; off > 0; off >>= 1) {
        es += __shfl_down(es, off, 64);
        edd += __shfl_down(edd, off, 64);
    }
    if (lane == 0) { e2s_o[d] = 0.5f * es; e2d_o[d] = 0.5f * edd; }
}

// ---------- conv2 GEMM via MFMA (h1h and W2P both in [c*4+h] k-order) ----------
__global__ __launch_bounds__(256) void k_gemm2(const _Float16* __restrict__ h1h,
        const _Float16* __restrict__ W2P, _Float16* __restrict__ xp2h)
{
    const int t = threadIdx.x;
    const int lane = t & 63, w = t >> 6;
    const int l15 = lane & 15, lq = lane >> 4;
    const int m0 = blockIdx.x * 64 + w * 16;
    const int mrow = m0 + l15;
    const _Float16* arow = h1h + (size_t)(m0 + l15) * 256;
    f16x8 af[8];
    #pragma unroll
    for (int ks = 0; ks < 8; ++ks) af[ks] = ldfrag(arow + ks * 32, lq);
    #pragma unroll
    for (int ct = 0; ct < 4; ++ct) {
        const _Float16* wrow = W2P + (size_t)(ct * 16 + l15) * 256;
        f32x4 acc = {0.f, 0.f, 0.f, 0.f};
        #pragma unroll
        for (int ks = 0; ks < 8; ++ks) {
            f16x8 wf = ldfrag(wrow + ks * 32, lq);
            acc = __builtin_amdgcn_mfma_f32_16x16x32_f16(wf, af[ks], acc, 0, 0, 0);
        }
        if (mrow < N_NODES) {
            union { uint2 u2; _Float16 e[4]; } o;
            o.e[0]=(_Float16)acc[0]; o.e[1]=(_Float16)acc[1];
            o.e[2]=(_Float16)acc[2]; o.e[3]=(_Float16)acc[3];
            *(uint2*)(xp2h + (size_t)mrow * 64 + ct * 16 + lq * 4) = o.u2;
        }
    }
}

// ---------- aggr2: edge-paired, 4B gathers, fused softmax + mean-pool ----------
__global__ __launch_bounds__(256) void k_aggr2(const int* __restrict__ rowptr,
        const int* __restrict__ csr_src, const float* __restrict__ e2s,
        const float* __restrict__ e2d, const _Float16* __restrict__ xp2h,
        const float* __restrict__ b2, const int* __restrict__ batch,
        float* __restrict__ pooled)
{
    const int lane = threadIdx.x & 63;
    const int w = __builtin_amdgcn_readfirstlane(threadIdx.x >> 6);
    const int d = blockIdx.x * 4 + w;
    if (d >= N_NODES) return;
    const int beg = rowptr[d], end = rowptr[d + 1];
    const float edv = e2d[d];
    const int li = lane & 31;
    const bool hB = lane >= 32;
    float acc0 = 0.f, acc1 = 0.f, den = 0.f;
    for (int jb = beg; jb < end; jb += 64) {
        int myj = jb + lane;
        int sv = 0;
        float p = 0.f;
        if (myj < end) {
            sv = csr_src[myj];
            p = __expf(lrelu(e2s[sv] + edv));
        }
        int nj = end - jb; if (nj > 64) nj = 64;
        int pr = (nj + 7) & ~7;          // 4 pairs per unrolled block
        for (int j = 0; j < pr; j += 8) {
            #pragma unroll
            for (int u = 0; u < 4; ++u) {
                int eA = j + 2 * u, eB = eA + 1;
                int sA = __shfl(sv, eA, 64), sB = __shfl(sv, eB, 64);
                float pA = __shfl(p, eA, 64), pB = __shfl(p, eB, 64);
                int s = hB ? sB : sA;
                float pp = hB ? pB : pA;
                union { unsigned int u1; _Float16 e[2]; } X;
                X.u1 = *(const unsigned int*)(xp2h + (size_t)s * 64 + li * 2);
                acc0 = fmaf(pp, (float)X.e[0], acc0);
                acc1 = fmaf(pp, (float)X.e[1], acc1);
                den += pp;
            }
        }
    }
    acc0 += __shfl_xor(acc0, 32, 64);
    acc1 += __shfl_xor(acc1, 32, 64);
    den  += __shfl_xor(den, 32, 64);
    float rdn = 1.f / den;
    int g = batch[d];
    if (!hB) {
        float v0 = acc0 * rdn + b2[2 * li];
        float v1 = acc1 * rdn + b2[2 * li + 1];
        atomicAdd(&pooled[g * 64 + 2 * li], v0);
        atomicAdd(&pooled[g * 64 + 2 * li + 1], v1);
    }
}

__global__ void k_mlp(const float* __restrict__ pooled, const float* __restrict__ cnt,
                      const float* __restrict__ Wh1, const float* __restrict__ bh1,
                      const float* __restrict__ Wh2, const float* __restrict__ bh2,
                      float* __restrict__ out)
{
    int g = threadIdx.x;   // 64 threads
    float inv = 1.f / fmaxf(cnt[g], 1.f);
    float p[64];
    #pragma unroll
    for (int c = 0; c < 64; ++c) p[c] = pooled[g * 64 + c] * inv;
    float acc2 = bh2[0];
    for (int j = 0; j < 16; ++j) {
        float z = bh1[j];
        #pragma unroll
        for (int c = 0; c < 64; ++c) z = fmaf(p[c], Wh1[c * 16 + j], z);
        z = fmaxf(z, 0.f);
        acc2 = fmaf(z, Wh2[j], acc2);
    }
    out[g] = 1.f / (1.f + expf(-acc2));
}

extern "C" void kernel_launch(void* const* d_in, const int* in_sizes, int n_in,
                              void* d_out, int out_size, void* d_ws, size_t ws_size,
                              hipStream_t stream)
{
    const float* x      = (const float*)d_in[0];
    const int*   ei     = (const int*)d_in[1];
    const int*   batch  = (const int*)d_in[2];
    const float* W1     = (const float*)d_in[3];
    const float* a1s    = (const float*)d_in[4];
    const float* a1d    = (const float*)d_in[5];
    const float* b1     = (const float*)d_in[6];
    const float* W2     = (const float*)d_in[7];
    const float* a2s    = (const float*)d_in[8];
    const float* a2d    = (const float*)d_in[9];
    const float* b2     = (const float*)d_in[10];
    const float* Wh1    = (const float*)d_in[11];
    const float* bh1    = (const float*)d_in[12];
    const float* Wh2    = (const float*)d_in[13];
    const float* bh2    = (const float*)d_in[14];
    float* out = (float*)d_out;

    float* ws = (float*)d_ws;
    size_t off = 0;
    _Float16* xp1h = (_Float16*)(ws + off); off += (size_t)N_NODES * 128;        // N*256 fp16
    _Float16* h1h  = (_Float16*)(ws + off); off += (size_t)(N_NODES + 64) * 128; // padded
    float* e1s    = ws + off; off += (size_t)N_NODES * 4;
    float* e1d    = ws + off; off += (size_t)N_NODES * 4;
    float* e2s    = ws + off; off += N_NODES;
    float* e2d    = ws + off; off += N_NODES;
    _Float16* xp2h = (_Float16*)(ws + off); off += (size_t)N_NODES * 32;         // N*64 fp16
    _Float16* W1P  = (_Float16*)(ws + off); off += 8192;
    _Float16* W2P  = (_Float16*)(ws + off); off += 8192;
    float* va1s   = ws + off; off += 256;
    float* va1d   = ws + off; off += 256;
    float* b1P    = ws + off; off += 256;
    float* va2sP  = ws + off; off += 256;
    float* va2dP  = ws + off; off += 256;
    float* pooled = ws + off; off += NG * HID;
    float* cnt    = ws + off; off += NG;
    int* rowptr   = (int*)(ws + off); off += N_NODES + 2;
    int* cursor   = (int*)(ws + off); off += N_NODES;
    int* csr_src  = (int*)(ws + off); off += EA;
    int* blksum   = (int*)(ws + off); off += NBLK;
    int* blkoff   = (int*)(ws + off); off += NBLK;
    // deg/incl alias h1h region (h1h first written by k_aggr1; CSR build done by then)
    int* deg  = (int*)h1h;
    int* incl = deg + N_NODES;

    const int BE = (EA + 255) / 256;
    const int BN = (N_NODES + 255) / 256;
    const int BW = (N_NODES + 3) / 4;      // wave-per-node grids
    const int BG = (N_NODES + 63) / 64;    // 64-row MFMA blocks

    hipLaunchKernelGGL(k_zero,   dim3(64),   dim3(256),  0, stream, deg, pooled, cnt);
    hipLaunchKernelGGL(k_deg,    dim3(BE),   dim3(256),  0, stream, ei, deg);
    hipLaunchKernelGGL(k_scan1,  dim3(NBLK), dim3(1024), 0, stream, deg, incl, blksum);
    hipLaunchKernelGGL(k_scan2p, dim3(1),    dim3(256),  0, stream,
                       blksum, blkoff, W1, a1s, a1d, W2, a2s, a2d, b1,
                       W1P, W2P, va1s, va1d, b1P, va2sP, va2dP);
    hipLaunchKernelGGL(k_scan3,  dim3(BN),   dim3(256),  0, stream,
                       incl, blkoff, deg, batch, rowptr, cursor, cnt);
    hipLaunchKernelGGL(k_fill,   dim3(BE),   dim3(256),  0, stream, ei, cursor, csr_src);

    hipLaunchKernelGGL(k_gemm1,  dim3(BG),   dim3(256),  0, stream,
                       x, W1P, va1s, va1d, xp1h, e1s, e1d);
    hipLaunchKernelGGL(k_aggr1,  dim3(BW),   dim3(256),  0, stream,
                       rowptr, csr_src, e1s, e1d, xp1h, b1P, va2sP, va2dP,
                       h1h, e2s, e2d);
    hipLaunchKernelGGL(k_gemm2,  dim3(BG),   dim3(256),  0, stream, h1h, W2P, xp2h);
    hipLaunchKernelGGL(k_aggr2,  dim3(BW),   dim3(256),  0, stream,
                       rowptr, csr_src, e2s, e2d, xp2h, b2, batch, pooled);

    hipLaunchKernelGGL(k_mlp, dim3(1), dim3(64), 0, stream,
                       pooled, cnt, Wh1, bh1, Wh2, bh2, out);
}

// Round 12
// 434.204 us; speedup vs baseline: 1.0896x; 1.0896x over previous
//
#include <hip/hip_runtime.h>
#include <math.h>

#define N_NODES 50000
#define N_EDGES 800000
#define EA (N_EDGES + N_NODES)   /* edges + self loops = 850000 */
#define HEADS 4
#define HID 64
#define NG 64
#define NEG_SLOPE 0.2f
#define SCAN_CHUNK 1024
#define NBLK ((N_NODES + SCAN_CHUNK - 1) / SCAN_CHUNK)   /* 49 */

typedef _Float16 f16x8 __attribute__((ext_vector_type(8)));
typedef float f32x4 __attribute__((ext_vector_type(4)));
struct h4 { _Float16 a, b, c, d; };   // 8-byte packed fp16 quad

__device__ inline float lrelu(float x) { return x > 0.f ? x : NEG_SLOPE * x; }

// MFMA 16x16x32 f16 operand fragment: elem j -> k = 16*(j>>2) + lq*4 + (j&3)
__device__ inline f16x8 ldfrag(const _Float16* __restrict__ p, int lq) {
    uint2 lo = *(const uint2*)(p + lq * 4);
    uint2 hi = *(const uint2*)(p + 16 + lq * 4);
    union { uint4 u; f16x8 v; } f;
    f.u = make_uint4(lo.x, lo.y, hi.x, hi.y);
    return f.v;
}

// ---------------- CSR build ----------------
__global__ void k_zero(int* __restrict__ deg, float* __restrict__ pooled,
                       float* __restrict__ cnt)
{
    int i = blockIdx.x * 256 + threadIdx.x;
    int st = gridDim.x * 256;
    for (int j = i; j < N_NODES; j += st) deg[j] = 0;
    if (i < NG * HID) pooled[i] = 0.f;
    if (i < NG) cnt[i] = 0.f;
}

__global__ void k_deg(const int* __restrict__ ei, int* __restrict__ deg)
{
    int e = blockIdx.x * 256 + threadIdx.x;
    if (e >= EA) return;
    int d = (e < N_EDGES) ? ei[N_EDGES + e] : e - N_EDGES;
    atomicAdd(&deg[d], 1);
}

__global__ __launch_bounds__(1024) void k_scan1(const int* __restrict__ deg,
        int* __restrict__ incl, int* __restrict__ blksum)
{
    __shared__ int sd[SCAN_CHUNK];
    int t = threadIdx.x;
    int i = blockIdx.x * SCAN_CHUNK + t;
    sd[t] = (i < N_NODES) ? deg[i] : 0;
    for (int off = 1; off < SCAN_CHUNK; off <<= 1) {
        __syncthreads();
        int u = (t >= off) ? sd[t - off] : 0;
        __syncthreads();
        sd[t] += u;
    }
    if (i < N_NODES) incl[i] = sd[t];
    if (t == SCAN_CHUNK - 1) blksum[blockIdx.x] = sd[t];
}

// ---------- scan2 + weight prep fused (1 block, 256 threads) ----------
// W1P[n'=c*4+h][k] = W1[k][h*64+c]   (256x64 fp16)  — conv1 swapped-MFMA operand
// W2P[n][k]        = W2[k][n]        (64x256 fp16)  — plain k-order
// va1s[k*4+h] = sum_c W1[k][h*64+c]*a1s[h][c]       (fp32, [k][h] for gemm1)
// va2s[k]     = sum_c W2[k][c]*a2s[c]               (fp32, plain)
__global__ __launch_bounds__(256) void k_scan2p(const int* __restrict__ blksum,
        int* __restrict__ blkoff, const float* __restrict__ W1,
        const float* __restrict__ a1s, const float* __restrict__ a1d,
        const float* __restrict__ W2, const float* __restrict__ a2s,
        const float* __restrict__ a2d,
        _Float16* __restrict__ W1P, _Float16* __restrict__ W2P,
        float* __restrict__ va1s, float* __restrict__ va1d,
        float* __restrict__ va2s, float* __restrict__ va2d)
{
    const int t = threadIdx.x;
    if (t == 0) {
        int acc = 0;
        for (int b = 0; b < NBLK; ++b) { blkoff[b] = acc; acc += blksum[b]; }
    }
    for (int i = t; i < 256 * 64; i += 256) {
        int np = i >> 6, k = i & 63;
        W1P[i] = (_Float16)W1[k * 256 + (np & 3) * 64 + (np >> 2)];
    }
    for (int i = t; i < 64 * 256; i += 256) {
        int n = i >> 8, k = i & 255;
        W2P[i] = (_Float16)W2[k * 64 + n];
    }
    {
        int k = t >> 2, h = t & 3;
        float ss = 0.f, sd = 0.f;
        for (int c = 0; c < 64; ++c) {
            float wv = W1[k * 256 + h * 64 + c];
            ss = fmaf(wv, a1s[h * 64 + c], ss);
            sd = fmaf(wv, a1d[h * 64 + c], sd);
        }
        va1s[t] = ss;   // [k][h]
        va1d[t] = sd;
    }
    {
        float ss = 0.f, sd = 0.f;
        for (int c = 0; c < 64; ++c) {
            float wv = W2[t * 64 + c];
            ss = fmaf(wv, a2s[c], ss);
            sd = fmaf(wv, a2d[c], sd);
        }
        va2s[t] = ss;
        va2d[t] = sd;
    }
}

__global__ void k_scan3(const int* __restrict__ incl, const int* __restrict__ blkoff,
                        const int* __restrict__ deg, const int* __restrict__ batch,
                        int* __restrict__ rowptr, int* __restrict__ cursor,
                        float* __restrict__ cnt)
{
    int i = blockIdx.x * 256 + threadIdx.x;
    bool act = i < N_NODES;
    if (act) {
        int v = incl[i] + blkoff[i >> 10];
        rowptr[i + 1] = v;
        cursor[i] = v - deg[i];
        if (i == 0) rowptr[0] = 0;
    }
    int g = act ? batch[i] : -1;
    int lane = threadIdx.x & 63;
    int g0 = __shfl(g, 0, 64);
    if (__all(g == g0)) {
        if (lane == 0 && g0 >= 0) atomicAdd(&cnt[g0], 64.f);
    } else if (act) {
        atomicAdd(&cnt[g], 1.f);
    }
}

__global__ void k_fill(const int* __restrict__ ei, int* __restrict__ cursor,
                       int* __restrict__ csr_src)
{
    int e = blockIdx.x * 256 + threadIdx.x;
    if (e >= EA) return;
    int s, d;
    if (e < N_EDGES) { s = ei[e]; d = ei[N_EDGES + e]; }
    else { s = e - N_EDGES; d = s; }
    int pos = atomicAdd(&cursor[d], 1);
    csr_src[pos] = s;
}

// ---------- conv1 GEMM via MFMA, fused fp32->fp16 cast + exact fp32 scores ----------
__global__ __launch_bounds__(256) void k_gemm1(const float* __restrict__ x,
        const _Float16* __restrict__ W1P, const float* __restrict__ va1s,
        const float* __restrict__ va1d, _Float16* __restrict__ xp1h,
        float* __restrict__ e1s, float* __restrict__ e1d)
{
    const int t = threadIdx.x;
    const int lane = t & 63, w = t >> 6;
    const int l15 = lane & 15, lq = lane >> 4;
    const int m0 = blockIdx.x * 64 + w * 16;
    const int mrow = m0 + l15;
    const int mc = mrow < N_NODES ? mrow : N_NODES - 1;
    const float* xr = x + (size_t)mc * 64;
    float4 x0 = *(const float4*)(xr + lq * 4);
    float4 x1 = *(const float4*)(xr + 16 + lq * 4);
    float4 x2 = *(const float4*)(xr + 32 + lq * 4);
    float4 x3 = *(const float4*)(xr + 48 + lq * 4);
    // exact fp32 scores: partial over this lane's 16 k's, reduce over lq groups
    const float4* vs4 = (const float4*)va1s;
    const float4* vd4 = (const float4*)va1d;
    float4 es = {0,0,0,0}, ed = {0,0,0,0};
    {
        float xv[16] = {x0.x,x0.y,x0.z,x0.w, x1.x,x1.y,x1.z,x1.w,
                        x2.x,x2.y,x2.z,x2.w, x3.x,x3.y,x3.z,x3.w};
        #pragma unroll
        for (int q = 0; q < 4; ++q) {
            int kb = q * 16 + lq * 4;
            #pragma unroll
            for (int j = 0; j < 4; ++j) {
                float v = xv[q * 4 + j];
                float4 a = vs4[kb + j], b = vd4[kb + j];
                es.x = fmaf(v, a.x, es.x); es.y = fmaf(v, a.y, es.y);
                es.z = fmaf(v, a.z, es.z); es.w = fmaf(v, a.w, es.w);
                ed.x = fmaf(v, b.x, ed.x); ed.y = fmaf(v, b.y, ed.y);
                ed.z = fmaf(v, b.z, ed.z); ed.w = fmaf(v, b.w, ed.w);
            }
        }
    }
    #pragma unroll
    for (int off = 16; off <= 32; off <<= 1) {
        es.x += __shfl_down(es.x, off, 64); es.y += __shfl_down(es.y, off, 64);
        es.z += __shfl_down(es.z, off, 64); es.w += __shfl_down(es.w, off, 64);
        ed.x += __shfl_down(ed.x, off, 64); ed.y += __shfl_down(ed.y, off, 64);
        ed.z += __shfl_down(ed.z, off, 64); ed.w += __shfl_down(ed.w, off, 64);
    }
    if (lq == 0 && mrow < N_NODES) {
        ((float4*)e1s)[mrow] = es;
        ((float4*)e1d)[mrow] = ed;
    }
    // fp16 fragments (same element order as ldfrag)
    union { f16x8 v; _Float16 e[8]; } u0, u1;
    u0.e[0]=(_Float16)x0.x; u0.e[1]=(_Float16)x0.y; u0.e[2]=(_Float16)x0.z; u0.e[3]=(_Float16)x0.w;
    u0.e[4]=(_Float16)x1.x; u0.e[5]=(_Float16)x1.y; u0.e[6]=(_Float16)x1.z; u0.e[7]=(_Float16)x1.w;
    u1.e[0]=(_Float16)x2.x; u1.e[1]=(_Float16)x2.y; u1.e[2]=(_Float16)x2.z; u1.e[3]=(_Float16)x2.w;
    u1.e[4]=(_Float16)x3.x; u1.e[5]=(_Float16)x3.y; u1.e[6]=(_Float16)x3.z; u1.e[7]=(_Float16)x3.w;
    #pragma unroll
    for (int ct = 0; ct < 16; ++ct) {
        const _Float16* wrow = W1P + (size_t)(ct * 16 + l15) * 64;
        f16x8 wf0 = ldfrag(wrow, lq);
        f16x8 wf1 = ldfrag(wrow + 32, lq);
        f32x4 acc = {0.f, 0.f, 0.f, 0.f};
        acc = __builtin_amdgcn_mfma_f32_16x16x32_f16(wf0, u0.v, acc, 0, 0, 0);
        acc = __builtin_amdgcn_mfma_f32_16x16x32_f16(wf1, u1.v, acc, 0, 0, 0);
        if (mrow < N_NODES) {
            union { uint2 u2; _Float16 e[4]; } o;
            o.e[0]=(_Float16)acc[0]; o.e[1]=(_Float16)acc[1];
            o.e[2]=(_Float16)acc[2]; o.e[3]=(_Float16)acc[3];
            *(uint2*)(xp1h + (size_t)mrow * 256 + ct * 16 + lq * 4) = o.u2;
        }
    }
}

// ---------- aggr1: wave per dst, 8B/lane gathers, unroll 8, fused epilogue ----------
__global__ __launch_bounds__(256) void k_aggr1(const int* __restrict__ rowptr,
        const int* __restrict__ csr_src, const float* __restrict__ e1s,
        const float* __restrict__ e1d, const _Float16* __restrict__ xp1h,
        const float* __restrict__ b1, const float* __restrict__ va2s,
        const float* __restrict__ va2d, _Float16* __restrict__ h1h,
        float* __restrict__ e2s_o, float* __restrict__ e2d_o)
{
    const int lane = threadIdx.x & 63;
    const int w = __builtin_amdgcn_readfirstlane(threadIdx.x >> 6);
    const int d = blockIdx.x * 4 + w;
    if (d >= N_NODES) return;
    const int beg = rowptr[d], end = rowptr[d + 1];
    const float4 edv = ((const float4*)e1d)[d];
    float a0 = 0.f, a1 = 0.f, a2 = 0.f, a3 = 0.f;
    float d0 = 0.f, d1 = 0.f, d2 = 0.f, d3 = 0.f;
    for (int jb = beg; jb < end; jb += 64) {
        int myj = jb + lane;
        int sv = 0;
        float px = 0.f, py = 0.f, pz = 0.f, pw = 0.f;
        if (myj < end) {
            sv = csr_src[myj];
            float4 q = ((const float4*)e1s)[sv];
            px = __expf(lrelu(q.x + edv.x));
            py = __expf(lrelu(q.y + edv.y));
            pz = __expf(lrelu(q.z + edv.z));
            pw = __expf(lrelu(q.w + edv.w));
        }
        int nj = end - jb; if (nj > 64) nj = 64;
        int njr = (nj + 7) & ~7;
        for (int j = 0; j < njr; j += 8) {
            #pragma unroll
            for (int k = 0; k < 8; ++k) {
                int s = __shfl(sv, j + k, 64);
                float p0 = __shfl(px, j + k, 64);
                float p1 = __shfl(py, j + k, 64);
                float p2 = __shfl(pz, j + k, 64);
                float p3 = __shfl(pw, j + k, 64);
                h4 xv = *(const h4*)(xp1h + (size_t)s * 256 + lane * 4);
                a0 = fmaf(p0, (float)xv.a, a0);
                a1 = fmaf(p1, (float)xv.b, a1);
                a2 = fmaf(p2, (float)xv.c, a2);
                a3 = fmaf(p3, (float)xv.d, a3);
                d0 += p0; d1 += p1; d2 += p2; d3 += p3;
            }
        }
    }
    float acc[4] = {a0 / d0, a1 / d1, a2 / d2, a3 / d3};
    float es = 0.f, edd = 0.f;
    #pragma unroll
    for (int hh = 0; hh < 4; ++hh) {
        float v = acc[hh] + b1[hh * 64 + lane];
        v = v > 0.f ? v : __expf(v) - 1.f;
        h1h[(size_t)d * 256 + hh * 64 + lane] = (_Float16)v;
        es  = fmaf(v, va2s[hh * 64 + lane], es);
        edd = fmaf(v, va2d[hh * 64 + lane], edd);
    }
    #pragma unroll
    for (int off = 32; off > 0; off >>= 1) {
        es += __shfl_down(es, off, 64);
        edd += __shfl_down(edd, off, 64);
    }
    if (lane == 0) { e2s_o[d] = es; e2d_o[d] = edd; }
}

// ---------- conv2 GEMM via MFMA (plain k-order) ----------
__global__ __launch_bounds__(256) void k_gemm2(const _Float16* __restrict__ h1h,
        const _Float16* __restrict__ W2P, _Float16* __restrict__ xp2h)
{
    const int t = threadIdx.x;
    const int lane = t & 63, w = t >> 6;
    const int l15 = lane & 15, lq = lane >> 4;
    const int m0 = blockIdx.x * 64 + w * 16;
    const int mrow = m0 + l15;
    const _Float16* arow = h1h + (size_t)(m0 + l15) * 256;
    f16x8 af[8];
    #pragma unroll
    for (int ks = 0; ks < 8; ++ks) af[ks] = ldfrag(arow + ks * 32, lq);
    #pragma unroll
    for (int ct = 0; ct < 4; ++ct) {
        const _Float16* wrow = W2P + (size_t)(ct * 16 + l15) * 256;
        f32x4 acc = {0.f, 0.f, 0.f, 0.f};
        #pragma unroll
        for (int ks = 0; ks < 8; ++ks) {
            f16x8 wf = ldfrag(wrow + ks * 32, lq);
            acc = __builtin_amdgcn_mfma_f32_16x16x32_f16(wf, af[ks], acc, 0, 0, 0);
        }
        if (mrow < N_NODES) {
            union { uint2 u2; _Float16 e[4]; } o;
            o.e[0]=(_Float16)acc[0]; o.e[1]=(_Float16)acc[1];
            o.e[2]=(_Float16)acc[2]; o.e[3]=(_Float16)acc[3];
            *(uint2*)(xp2h + (size_t)mrow * 64 + ct * 16 + lq * 4) = o.u2;
        }
    }
}

// ---------- aggr2: wave per dst, 2B/lane gathers, unroll 16, fused mean-pool ----------
__global__ __launch_bounds__(256) void k_aggr2(const int* __restrict__ rowptr,
        const int* __restrict__ csr_src, const float* __restrict__ e2s,
        const float* __restrict__ e2d, const _Float16* __restrict__ xp2h,
        const float* __restrict__ b2, const int* __restrict__ batch,
        float* __restrict__ pooled)
{
    const int lane = threadIdx.x & 63;
    const int w = __builtin_amdgcn_readfirstlane(threadIdx.x >> 6);
    const int d = blockIdx.x * 4 + w;
    if (d >= N_NODES) return;
    const int beg = rowptr[d], end = rowptr[d + 1];
    const float edv = e2d[d];
    float acc = 0.f, den = 0.f;
    for (int jb = beg; jb < end; jb += 64) {
        int myj = jb + lane;
        int sv = 0;
        float p = 0.f;
        if (myj < end) {
            sv = csr_src[myj];
            p = __expf(lrelu(e2s[sv] + edv));
        }
        int nj = end - jb; if (nj > 64) nj = 64;
        int njr = (nj + 15) & ~15;
        for (int j = 0; j < njr; j += 16) {
            #pragma unroll
            for (int k = 0; k < 16; ++k) {
                int s = __shfl(sv, j + k, 64);
                float pv = __shfl(p, j + k, 64);
                acc = fmaf(pv, (float)xp2h[(size_t)s * 64 + lane], acc);
                den += pv;
            }
        }
    }
    float val = acc / den + b2[lane];
    int g = batch[d];
    atomicAdd(&pooled[g * 64 + lane], val);
}

__global__ void k_mlp(const float* __restrict__ pooled, const float* __restrict__ cnt,
                      const float* __restrict__ Wh1, const float* __restrict__ bh1,
                      const float* __restrict__ Wh2, const float* __restrict__ bh2,
                      float* __restrict__ out)
{
    int g = threadIdx.x;   // 64 threads
    float inv = 1.f / fmaxf(cnt[g], 1.f);
    float p[64];
    #pragma unroll
    for (int c = 0; c < 64; ++c) p[c] = pooled[g * 64 + c] * inv;
    float acc2 = bh2[0];
    for (int j = 0; j < 16; ++j) {
        float z = bh1[j];
        #pragma unroll
        for (int c = 0; c < 64; ++c) z = fmaf(p[c], Wh1[c * 16 + j], z);
        z = fmaxf(z, 0.f);
        acc2 = fmaf(z, Wh2[j], acc2);
    }
    out[g] = 1.f / (1.f + expf(-acc2));
}

extern "C" void kernel_launch(void* const* d_in, const int* in_sizes, int n_in,
                              void* d_out, int out_size, void* d_ws, size_t ws_size,
                              hipStream_t stream)
{
    const float* x      = (const float*)d_in[0];
    const int*   ei     = (const int*)d_in[1];
    const int*   batch  = (const int*)d_in[2];
    const float* W1     = (const float*)d_in[3];
    const float* a1s    = (const float*)d_in[4];
    const float* a1d    = (const float*)d_in[5];
    const float* b1     = (const float*)d_in[6];
    const float* W2     = (const float*)d_in[7];
    const float* a2s    = (const float*)d_in[8];
    const float* a2d    = (const float*)d_in[9];
    const float* b2     = (const float*)d_in[10];
    const float* Wh1    = (const float*)d_in[11];
    const float* bh1    = (const float*)d_in[12];
    const float* Wh2    = (const float*)d_in[13];
    const float* bh2    = (const float*)d_in[14];
    float* out = (float*)d_out;

    float* ws = (float*)d_ws;
    size_t off = 0;
    _Float16* xp1h = (_Float16*)(ws + off); off += (size_t)N_NODES * 128;        // N*256 fp16
    _Float16* h1h  = (_Float16*)(ws + off); off += (size_t)(N_NODES + 64) * 128; // padded
    float* e1s    = ws + off; off += (size_t)N_NODES * 4;
    float* e1d    = ws + off; off += (size_t)N_NODES * 4;
    float* e2s    = ws + off; off += N_NODES;
    float* e2d    = ws + off; off += N_NODES;
    _Float16* xp2h = (_Float16*)(ws + off); off += (size_t)N_NODES * 32;         // N*64 fp16
    _Float16* W1P  = (_Float16*)(ws + off); off += 8192;
    _Float16* W2P  = (_Float16*)(ws + off); off += 8192;
    float* va1s   = ws + off; off += 256;
    float* va1d   = ws + off; off += 256;
    float* va2s   = ws + off; off += 256;
    float* va2d   = ws + off; off += 256;
    float* pooled = ws + off; off += NG * HID;
    float* cnt    = ws + off; off += NG;
    int* rowptr   = (int*)(ws + off); off += N_NODES + 2;
    int* cursor   = (int*)(ws + off); off += N_NODES;
    int* csr_src  = (int*)(ws + off); off += EA;
    int* blksum   = (int*)(ws + off); off += NBLK;
    int* blkoff   = (int*)(ws + off); off += NBLK;
    // deg/incl alias h1h region (h1h first written by k_aggr1; CSR build done by then)
    int* deg  = (int*)h1h;
    int* incl = deg + N_NODES;

    const int BE = (EA + 255) / 256;
    const int BN = (N_NODES + 255) / 256;
    const int BW = (N_NODES + 3) / 4;      // wave-per-node grids
    const int BG = (N_NODES + 63) / 64;    // 64-row MFMA blocks

    hipLaunchKernelGGL(k_zero,   dim3(64),   dim3(256),  0, stream, deg, pooled, cnt);
    hipLaunchKernelGGL(k_deg,    dim3(BE),   dim3(256),  0, stream, ei, deg);
    hipLaunchKernelGGL(k_scan1,  dim3(NBLK), dim3(1024), 0, stream, deg, incl, blksum);
    hipLaunchKernelGGL(k_scan2p, dim3(1),    dim3(256),  0, stream,
                       blksum, blkoff, W1, a1s, a1d, W2, a2s, a2d,
                       W1P, W2P, va1s, va1d, va2s, va2d);
    hipLaunchKernelGGL(k_scan3,  dim3(BN),   dim3(256),  0, stream,
                       incl, blkoff, deg, batch, rowptr, cursor, cnt);
    hipLaunchKernelGGL(k_fill,   dim3(BE),   dim3(256),  0, stream, ei, cursor, csr_src);

    hipLaunchKernelGGL(k_gemm1,  dim3(BG),   dim3(256),  0, stream,
                       x, W1P, va1s, va1d, xp1h, e1s, e1d);
    hipLaunchKernelGGL(k_aggr1,  dim3(BW),   dim3(256),  0, stream,
                       rowptr, csr_src, e1s, e1d, xp1h, b1, va2s, va2d,
                       h1h, e2s, e2d);
    hipLaunchKernelGGL(k_gemm2,  dim3(BG),   dim3(256),  0, stream, h1h, W2P, xp2h);
    hipLaunchKernelGGL(k_aggr2,  dim3(BW),   dim3(256),  0, stream,
                       rowptr, csr_src, e2s, e2d, xp2h, b2, batch, pooled);

    hipLaunchKernelGGL(k_mlp, dim3(1), dim3(64), 0, stream,
                       pooled, cnt, Wh1, bh1, Wh2, bh2, out);
}